// Round 16
// baseline (713.896 us; speedup 1.0000x reference)
//
#include <hip/hip_runtime.h>
#include <hip/hip_bf16.h>

typedef __attribute__((ext_vector_type(8))) short short8;
typedef __attribute__((ext_vector_type(4))) float f32x4;
typedef __attribute__((ext_vector_type(2))) unsigned int u32x2;
typedef unsigned short u16;
typedef unsigned int u32;
typedef unsigned long long u64;

#define NODES 16384
#define CHN 128
#define NEDGE 524288
#define NG 16
#define NPGC 1024
#define NHEAD 4
#define HDIM 32
#define NLAYER 4
#define CL 0.2550348281f   // log2(e)/sqrt(HDIM), folded into Q at QKV store

#if __has_builtin(__builtin_amdgcn_exp2f)
#define EXP2(x) __builtin_amdgcn_exp2f(x)
#else
#define EXP2(x) exp2f(x)
#endif

__device__ __forceinline__ float bf2f(u16 u) {
    union { u32 u; float f; } c; c.u = ((u32)u) << 16; return c.f;
}
__device__ __forceinline__ u16 f2bf(float f) {
    union { float f; u32 u; } c; c.f = f;
    u32 r = c.u + 0x7fffu + ((c.u >> 16) & 1u);
    return (u16)(r >> 16);
}
__device__ __forceinline__ void fsplit(float f, u16& hi, u16& lo) {
    u16 h = f2bf(f);
    hi = h;
    lo = f2bf(f - bf2f(h));
}
__device__ __forceinline__ u32 cvtpk_bf16(float a, float b) {
    u32 r;
    asm("v_cvt_pk_bf16_f32 %0, %1, %2" : "=v"(r) : "v"(a), "v"(b));
    return r;
}

#define MFMA16(a, b, c) __builtin_amdgcn_mfma_f32_16x16x32_bf16((a), (b), (c), 0, 0, 0)

__device__ __forceinline__ short8 ld_frag(const u16* p) {
    return *reinterpret_cast<const short8*>(p);
}

// ---------------- setup kernels ----------------

struct SplitJobs {
    const float* src[8];
    u16* hi[8];
    u16* lo[8];
    int blk_end[8];
};

__global__ void k_split8(SplitJobs jobs) {
    int b = blockIdx.x;
    int seg = 0;
    while (b >= jobs.blk_end[seg]) ++seg;
    int base = seg ? jobs.blk_end[seg - 1] : 0;
    int i = (b - base) * 256 + threadIdx.x;
    u16 h, l;
    fsplit(jobs.src[seg][i], h, l);
    jobs.hi[seg][i] = h;
    jobs.lo[seg][i] = l;
}

__global__ void k_bnprep(const float* __restrict__ g, const float* __restrict__ b,
                         const float* __restrict__ m, const float* __restrict__ v,
                         float* __restrict__ scale, float* __restrict__ shift) {
    int i = blockIdx.x * 256 + threadIdx.x;
    if (i < NLAYER * 3 * CHN) {
        float s = g[i] * rsqrtf(v[i] + 1e-5f);
        scale[i] = s;
        shift[i] = b[i] - m[i] * s;
    }
}

__global__ void k_zero_u32(u32* __restrict__ p, int n) {
    int i = blockIdx.x * 256 + threadIdx.x;
    if (i < n) p[i] = 0u;
}

__global__ void k_count(const int* __restrict__ dst, u32* __restrict__ counts) {
    int e = blockIdx.x * 256 + threadIdx.x;
    if (e < NEDGE) atomicAdd(&counts[dst[e]], 1u);
}

__global__ void k_scan(const u32* __restrict__ counts, u32* __restrict__ offsets,
                       u32* __restrict__ cursor) {
    __shared__ u32 part[256];
    int t = threadIdx.x;
    int base = t * 64;
    u32 s = 0;
    for (int i = 0; i < 64; ++i) s += counts[base + i];
    part[t] = s;
    __syncthreads();
    for (int off = 1; off < 256; off <<= 1) {
        u32 val = (t >= off) ? part[t - off] : 0u;
        __syncthreads();
        part[t] += val;
        __syncthreads();
    }
    u32 run = (t == 0) ? 0u : part[t - 1];
    for (int i = 0; i < 64; ++i) {
        offsets[base + i] = run;
        cursor[base + i] = run;
        run += counts[base + i];
    }
    if (t == 255) offsets[NODES] = run;
}

// combined (src, attr-bits) 8B store: halves scattered-write line traffic
__global__ void k_fill(const int* __restrict__ src, const int* __restrict__ dst,
                       const float* __restrict__ eattr, u32* __restrict__ cursor,
                       int2* __restrict__ csr_sa) {
    int e = blockIdx.x * 256 + threadIdx.x;
    if (e >= NEDGE) return;
    int d = dst[e];
    u32 p = atomicAdd(&cursor[d], 1u);
    csr_sa[p] = make_int2(src[e], __float_as_int(eattr[e]));
}

// ---- FAT kernel 1: GINE aggregation (blocks < NODES/4) ∥ QKV GEMM (rest) ----
// agg: transposed lane layout — lane = eg*16+cl; 16 lanes cover one h-row (16B
// chunks), 4 edges per load instruction, 8-deep unroll -> 32 edges in flight.

__global__ __launch_bounds__(256) void k_aggqkv(
    // agg args
    const u16* __restrict__ h_hi, const float* __restrict__ h_f32,
    const u32* __restrict__ offsets, const int2* __restrict__ csr_sa,
    const float* __restrict__ ew, const float* __restrict__ eb,
    u16* __restrict__ z_hi, u16* __restrict__ z_lo,
    // qkv args
    const u16* __restrict__ h_lo, const u16* __restrict__ Whi,
    const u16* __restrict__ Wlo, const float* __restrict__ bias,
    u16* __restrict__ q_hi, u16* __restrict__ q_lo,
    u16* __restrict__ k_hi, u16* __restrict__ k_lo,
    u16* __restrict__ vt_hi) {
    int tid = threadIdx.x;
    int wave = tid >> 6, lane = tid & 63;
    if (blockIdx.x < NODES / 4) {
        // ---- aggregation: 4 nodes/block, one wave/node ----
        int node = blockIdx.x * 4 + wave;
        int eg = lane >> 4;        // edge subgroup 0..3
        int cl = lane & 15;        // channel chunk
        int c0 = cl * 8;
        float w[8], bb[8];
#pragma unroll
        for (int c = 0; c < 8; ++c) { w[c] = ew[c0 + c]; bb[c] = eb[c0 + c]; }
        u32 beg = offsets[node], end = offsets[node + 1];
        u32 n = end - beg;
        float acc[8] = {};
        u32 i = beg;
        // main loop: 32 edges per iteration (4 per subgroup-instr x 8 unroll)
        for (; i + 32 <= end; i += 32) {
            int2 es[8];
            short8 us[8];
#pragma unroll
            for (int j = 0; j < 8; ++j) es[j] = csr_sa[i + eg + j * 4];
#pragma unroll
            for (int j = 0; j < 8; ++j)
                us[j] = ld_frag(h_hi + (size_t)es[j].x * CHN + c0);
#pragma unroll
            for (int j = 0; j < 8; ++j) {
                float a = __int_as_float(es[j].y);
#pragma unroll
                for (int c = 0; c < 8; ++c) {
                    float f = bf2f((u16)us[j][c]);
                    acc[c] += fmaxf(f + a * w[c] + bb[c], 0.f);
                }
            }
        }
        // tail: 4-way parallel across subgroups
        for (u32 t = i + eg; t < end; t += 4) {
            int2 e = csr_sa[t];
            short8 u = ld_frag(h_hi + (size_t)e.x * CHN + c0);
            float a = __int_as_float(e.y);
#pragma unroll
            for (int c = 0; c < 8; ++c) {
                float f = bf2f((u16)u[c]);
                acc[c] += fmaxf(f + a * w[c] + bb[c], 0.f);
            }
        }
        // cross-subgroup combine (lanes cl, cl+16, cl+32, cl+48)
#pragma unroll
        for (int c = 0; c < 8; ++c) {
            acc[c] += __shfl_xor(acc[c], 16);
            acc[c] += __shfl_xor(acc[c], 32);
        }
        if (eg == 0) {
            size_t idx = (size_t)node * CHN + c0;
            union { u16 u[8]; short8 s; } zh, zl;
#pragma unroll
            for (int c = 0; c < 8; ++c) {
                float z = h_f32[idx + c] + acc[c];
                u16 hh, ll;
                fsplit(z, hh, ll);
                zh.u[c] = hh; zl.u[c] = ll;
            }
            *reinterpret_cast<short8*>(z_hi + idx) = zh.s;
            *reinterpret_cast<short8*>(z_lo + idx) = zl.s;
        }
        return;
    }
    // ---- QKV GEMM; Q pre-scaled by CL ----
    const int K = 128;
    int id = blockIdx.x - NODES / 4;
    int bx = id & 255, ny = id >> 8;
    int lr = lane & 15, lg = lane >> 4;
    int r0 = bx * 64 + wave * 16;
    int nb = ny * 32;
    f32x4 acc[2] = {};
    size_t arow = (size_t)(r0 + lr) * K + lg * 8;
    for (int ks = 0; ks < K; ks += 32) {
        short8 ah = ld_frag(h_hi + arow + ks);
        short8 al = ld_frag(h_lo + arow + ks);
#pragma unroll
        for (int n = 0; n < 2; ++n) {
            size_t wrow = (size_t)(nb + n * 16 + lr) * K + ks + lg * 8;
            short8 wh = ld_frag(Whi + wrow);
            short8 wl = ld_frag(Wlo + wrow);
            acc[n] = MFMA16(ah, wh, acc[n]);
            acc[n] = MFMA16(al, wh, acc[n]);
            acc[n] = MFMA16(ah, wl, acc[n]);
        }
    }
#pragma unroll
    for (int n = 0; n < 2; ++n) {
        int col = nb + n * 16 + lr;
        int region = col >> 7;
        int c = col & 127;
        int hh = c >> 5, d = c & 31;
        float bs = bias[col];
#pragma unroll
        for (int r = 0; r < 4; ++r) {
            int row = r0 + lg * 4 + r;
            float v = acc[n][r] + bs;
            int g = row >> 10, p = row & 1023;
            size_t gh = (size_t)(g * NHEAD + hh);
            if (region == 0) {
                u16 vh, vl;
                fsplit(v * CL, vh, vl);
                size_t o = (gh * NPGC + p) * HDIM + d;
                q_hi[o] = vh; q_lo[o] = vl;
            } else if (region == 1) {
                u16 vh, vl;
                fsplit(v, vh, vl);
                size_t o = (gh * NPGC + p) * HDIM + d;
                k_hi[o] = vh; k_lo[o] = vl;
            } else {
                vt_hi[(gh * HDIM + d) * NPGC + p] = f2bf(v);
            }
        }
    }
}

// ------ split GEMM (16x32 wave tile) — used for node projection ------

__global__ __launch_bounds__(256) void k_gemm(
    const u16* __restrict__ Ahi, const u16* __restrict__ Alo,
    const u16* __restrict__ Whi, const u16* __restrict__ Wlo,
    const float* __restrict__ bias, float* __restrict__ out_f32,
    u16* __restrict__ out_hi, u16* __restrict__ out_lo, int K, int Nc) {
    int tid = threadIdx.x;
    int wave = tid >> 6, lane = tid & 63;
    int lr = lane & 15, lg = lane >> 4;
    int r0 = blockIdx.x * 64 + wave * 16;
    int nb = blockIdx.y * 32;
    f32x4 acc[2] = {};
    size_t arow = (size_t)(r0 + lr) * K + lg * 8;
    for (int ks = 0; ks < K; ks += 32) {
        short8 ah = ld_frag(Ahi + arow + ks);
        short8 al = ld_frag(Alo + arow + ks);
#pragma unroll
        for (int n = 0; n < 2; ++n) {
            size_t wrow = (size_t)(nb + n * 16 + lr) * K + ks + lg * 8;
            short8 wh = ld_frag(Whi + wrow);
            short8 wl = ld_frag(Wlo + wrow);
            acc[n] = MFMA16(ah, wh, acc[n]);
            acc[n] = MFMA16(al, wh, acc[n]);
            acc[n] = MFMA16(ah, wl, acc[n]);
        }
    }
#pragma unroll
    for (int n = 0; n < 2; ++n) {
        int col = nb + n * 16 + lr;
        float bs = bias[col];
#pragma unroll
        for (int r = 0; r < 4; ++r) {
            int row = r0 + lg * 4 + r;
            size_t oidx = (size_t)row * Nc + col;
            float v = acc[n][r] + bs;
            out_f32[oidx] = v;
            u16 hh, ll;
            fsplit(v, hh, ll);
            out_hi[oidx] = hh; out_lo[oidx] = ll;
        }
    }
}

// ---- FAT kernel 2: fused GINE MLP (blocks < 256) ∥ flash attention (rest) ----
// gine: 64 rows/block, 4 row-groups/wave (12 MFMA per weight-pair load).

__global__ __launch_bounds__(256) void k_gineattn(
    // gine args
    const u16* __restrict__ zhi, const u16* __restrict__ zlo,
    const u16* __restrict__ w1hi, const u16* __restrict__ w1lo,
    const float* __restrict__ b1,
    const u16* __restrict__ w2hi, const u16* __restrict__ w2lo,
    const float* __restrict__ b2, const float* __restrict__ resid,
    const float* __restrict__ bnsc, const float* __restrict__ bnsh,
    float* __restrict__ h1out,
    // attn args
    const u16* __restrict__ qhi, const u16* __restrict__ qlo,
    const u16* __restrict__ khi, const u16* __restrict__ klo,
    const u16* __restrict__ vthi,
    u16* __restrict__ aohi, u16* __restrict__ aolo) {
    __shared__ __align__(16) u16 smem[128][136];   // gine: t_hi rows 0-63, t_lo rows 64-127
    int tid = threadIdx.x;
    int wave = tid >> 6, lane = tid & 63;
    int lr = lane & 15, lg = lane >> 4;
    if (blockIdx.x < NODES / 64) {
        // ---------------- GINE MLP: 64 rows/block, 4 row-groups/wave ----------------
        int r0 = blockIdx.x * 64;
        int cb = wave * 32;
        {
            f32x4 acc[4][2] = {};
            for (int ks = 0; ks < CHN; ks += 32) {
                short8 ah[4], al[4];
#pragma unroll
                for (int rg = 0; rg < 4; ++rg) {
                    size_t arow = (size_t)(r0 + rg * 16 + lr) * CHN + ks + lg * 8;
                    ah[rg] = ld_frag(zhi + arow);
                    al[rg] = ld_frag(zlo + arow);
                }
#pragma unroll
                for (int n = 0; n < 2; ++n) {
                    size_t wrow = (size_t)(cb + n * 16 + lr) * CHN + ks + lg * 8;
                    short8 wh = ld_frag(w1hi + wrow);
                    short8 wl = ld_frag(w1lo + wrow);
#pragma unroll
                    for (int rg = 0; rg < 4; ++rg) {
                        acc[rg][n] = MFMA16(ah[rg], wh, acc[rg][n]);
                        acc[rg][n] = MFMA16(al[rg], wh, acc[rg][n]);
                        acc[rg][n] = MFMA16(ah[rg], wl, acc[rg][n]);
                    }
                }
            }
#pragma unroll
            for (int rg = 0; rg < 4; ++rg)
#pragma unroll
                for (int n = 0; n < 2; ++n) {
                    int col = cb + n * 16 + lr;
                    float bs = b1[col];
#pragma unroll
                    for (int r = 0; r < 4; ++r) {
                        float v = fmaxf(acc[rg][n][r] + bs, 0.f);
                        u16 hh, ll;
                        fsplit(v, hh, ll);
                        int rl = rg * 16 + lg * 4 + r;
                        smem[rl][col] = hh;
                        smem[64 + rl][col] = ll;
                    }
                }
        }
        __syncthreads();
        {
            f32x4 acc[4][2] = {};
            for (int ks = 0; ks < CHN; ks += 32) {
                short8 ah[4], al[4];
#pragma unroll
                for (int rg = 0; rg < 4; ++rg) {
                    ah[rg] = ld_frag(&smem[rg * 16 + lr][ks + lg * 8]);
                    al[rg] = ld_frag(&smem[64 + rg * 16 + lr][ks + lg * 8]);
                }
#pragma unroll
                for (int n = 0; n < 2; ++n) {
                    size_t wrow = (size_t)(cb + n * 16 + lr) * CHN + ks + lg * 8;
                    short8 wh = ld_frag(w2hi + wrow);
                    short8 wl = ld_frag(w2lo + wrow);
#pragma unroll
                    for (int rg = 0; rg < 4; ++rg) {
                        acc[rg][n] = MFMA16(ah[rg], wh, acc[rg][n]);
                        acc[rg][n] = MFMA16(al[rg], wh, acc[rg][n]);
                        acc[rg][n] = MFMA16(ah[rg], wl, acc[rg][n]);
                    }
                }
            }
#pragma unroll
            for (int rg = 0; rg < 4; ++rg)
#pragma unroll
                for (int n = 0; n < 2; ++n) {
                    int col = cb + n * 16 + lr;
                    float bs = b2[col], sc = bnsc[col], sh = bnsh[col];
#pragma unroll
                    for (int r = 0; r < 4; ++r) {
                        int row = r0 + rg * 16 + lg * 4 + r;
                        size_t oidx = (size_t)row * CHN + col;
                        float v = acc[rg][n][r] + bs + resid[oidx];
                        h1out[oidx] = v * sc + sh;
                    }
                }
        }
        return;
    }
    // ---------------- attention: swapped QK^T, dual-stream, defer-max ----------------
    int id = blockIdx.x - NODES / 64;
    int gh = id & 63;           // id%8==gh%8 -> per-gh XCD locality (256 offset %8==0)
    int bx = id >> 6;           // 0..7
    int qA = bx * 128 + wave * 32;
    int qB = qA + 16;
    size_t base = (size_t)gh * NPGC * HDIM;
    size_t vbase = (size_t)gh * HDIM * NPGC;
    short8 qhA = ld_frag(qhi + base + (size_t)(qA + lr) * HDIM + lg * 8);
    short8 qlA = ld_frag(qlo + base + (size_t)(qA + lr) * HDIM + lg * 8);
    short8 qhB = ld_frag(qhi + base + (size_t)(qB + lr) * HDIM + lg * 8);
    short8 qlB = ld_frag(qlo + base + (size_t)(qB + lr) * HDIM + lg * 8);
    const u16* Kh = khi + base;
    const u16* Kl = klo + base;
    const u16* Vh = vthi + vbase;
    f32x4 o0A = {}, o1A = {}, o0B = {}, o1B = {};
    f32x4 lsA = {}, lsB = {};
    float mA = -1e30f, mB = -1e30f;
    const f32x4 zero = {};
    u16 (*plds)[136] = (u16 (*)[136])&smem[wave * 16][0];
    for (int kv = 0; kv < NPGC; kv += 128) {
        f32x4 sA[8], sB[8];
        __builtin_amdgcn_s_setprio(1);
#pragma unroll
        for (int f = 0; f < 8; ++f) {
            size_t kr = (size_t)(kv + f * 16 + lr) * HDIM + lg * 8;
            short8 kh = ld_frag(Kh + kr);
            short8 kl2 = ld_frag(Kl + kr);
            sA[f] = MFMA16(kh, qlA, MFMA16(kl2, qhA, MFMA16(kh, qhA, zero)));
            sB[f] = MFMA16(kh, qlB, MFMA16(kl2, qhB, MFMA16(kh, qhB, zero)));
        }
        __builtin_amdgcn_s_setprio(0);
        // softmax A: defer-max fast path
        {
            f32x4 mm = sA[0];
#pragma unroll
            for (int f = 1; f < 8; ++f)
#pragma unroll
                for (int i = 0; i < 4; ++i) mm[i] = fmaxf(mm[i], sA[f][i]);
            float mx = fmaxf(fmaxf(mm[0], mm[1]), fmaxf(mm[2], mm[3]));
            if (!__all(mx <= mA + 8.f)) {
                mx = fmaxf(mx, __shfl_xor(mx, 16));
                mx = fmaxf(mx, __shfl_xor(mx, 32));
                float mn = fmaxf(mA, mx);
                float corr = EXP2(mA - mn);
                mA = mn;
#pragma unroll
                for (int i = 0; i < 4; ++i) {
                    lsA[i] *= corr;
                    o0A[i] *= corr; o1A[i] *= corr;
                }
            }
#pragma unroll
            for (int f = 0; f < 8; ++f)
#pragma unroll
                for (int i = 0; i < 4; ++i) sA[f][i] = EXP2(sA[f][i] - mA);
            f32x4 s4 = sA[0];
#pragma unroll
            for (int f = 1; f < 8; ++f)
#pragma unroll
                for (int i = 0; i < 4; ++i) s4[i] += sA[f][i];
            lsA += s4;
#pragma unroll
            for (int f = 0; f < 8; ++f) {
                u32x2 wv;
                wv[0] = cvtpk_bf16(sA[f][0], sA[f][1]);
                wv[1] = cvtpk_bf16(sA[f][2], sA[f][3]);
                *reinterpret_cast<u32x2*>(&plds[lr][f * 16 + lg * 4]) = wv;
            }
        }
        // PV A (V frags kept for B)
        short8 vs0[4], vs1[4];
        __builtin_amdgcn_s_setprio(1);
#pragma unroll
        for (int kk = 0; kk < 4; ++kk) {
            short8 pf = ld_frag(&plds[lr][kk * 32 + lg * 8]);
            vs0[kk] = ld_frag(Vh + (size_t)lr * NPGC + kv + kk * 32 + lg * 8);
            vs1[kk] = ld_frag(Vh + (size_t)(16 + lr) * NPGC + kv + kk * 32 + lg * 8);
            o0A = MFMA16(vs0[kk], pf, o0A);
            o1A = MFMA16(vs1[kk], pf, o1A);
        }
        __builtin_amdgcn_s_setprio(0);
        // softmax B
        {
            f32x4 mm = sB[0];
#pragma unroll
            for (int f = 1; f < 8; ++f)
#pragma unroll
                for (int i = 0; i < 4; ++i) mm[i] = fmaxf(mm[i], sB[f][i]);
            float mx = fmaxf(fmaxf(mm[0], mm[1]), fmaxf(mm[2], mm[3]));
            if (!__all(mx <= mB + 8.f)) {
                mx = fmaxf(mx, __shfl_xor(mx, 16));
                mx = fmaxf(mx, __shfl_xor(mx, 32));
                float mn = fmaxf(mB, mx);
                float corr = EXP2(mB - mn);
                mB = mn;
#pragma unroll
                for (int i = 0; i < 4; ++i) {
                    lsB[i] *= corr;
                    o0B[i] *= corr; o1B[i] *= corr;
                }
            }
#pragma unroll
            for (int f = 0; f < 8; ++f)
#pragma unroll
                for (int i = 0; i < 4; ++i) sB[f][i] = EXP2(sB[f][i] - mB);
            f32x4 s4 = sB[0];
#pragma unroll
            for (int f = 1; f < 8; ++f)
#pragma unroll
                for (int i = 0; i < 4; ++i) s4[i] += sB[f][i];
            lsB += s4;
#pragma unroll
            for (int f = 0; f < 8; ++f) {
                u32x2 wv;
                wv[0] = cvtpk_bf16(sB[f][0], sB[f][1]);
                wv[1] = cvtpk_bf16(sB[f][2], sB[f][3]);
                *reinterpret_cast<u32x2*>(&plds[lr][f * 16 + lg * 4]) = wv;
            }
        }
        // PV B
        __builtin_amdgcn_s_setprio(1);
#pragma unroll
        for (int kk = 0; kk < 4; ++kk) {
            short8 pf = ld_frag(&plds[lr][kk * 32 + lg * 8]);
            o0B = MFMA16(vs0[kk], pf, o0B);
            o1B = MFMA16(vs1[kk], pf, o1B);
        }
        __builtin_amdgcn_s_setprio(0);
    }
    float lA = (lsA[0] + lsA[1]) + (lsA[2] + lsA[3]);
    lA += __shfl_xor(lA, 16);
    lA += __shfl_xor(lA, 32);
    float lB = (lsB[0] + lsB[1]) + (lsB[2] + lsB[3]);
    lB += __shfl_xor(lB, 16);
    lB += __shfl_xor(lB, 32);
    int g = gh >> 2, hh = gh & 3;
    {
        float inv = 1.f / lA;
        size_t obase = ((size_t)g * NPGC + qA + lr) * CHN + hh * HDIM;
        union { u16 u[4]; u64 v; } p0h, p0l, p1h, p1l;
#pragma unroll
        for (int i = 0; i < 4; ++i) {
            u16 a, b;
            fsplit(o0A[i] * inv, a, b); p0h.u[i] = a; p0l.u[i] = b;
            fsplit(o1A[i] * inv, a, b); p1h.u[i] = a; p1l.u[i] = b;
        }
        *reinterpret_cast<u64*>(aohi + obase + lg * 4) = p0h.v;
        *reinterpret_cast<u64*>(aolo + obase + lg * 4) = p0l.v;
        *reinterpret_cast<u64*>(aohi + obase + 16 + lg * 4) = p1h.v;
        *reinterpret_cast<u64*>(aolo + obase + 16 + lg * 4) = p1l.v;
    }
    {
        float inv = 1.f / lB;
        size_t obase = ((size_t)g * NPGC + qB + lr) * CHN + hh * HDIM;
        union { u16 u[4]; u64 v; } p0h, p0l, p1h, p1l;
#pragma unroll
        for (int i = 0; i < 4; ++i) {
            u16 a, b;
            fsplit(o0B[i] * inv, a, b); p0h.u[i] = a; p0l.u[i] = b;
            fsplit(o1B[i] * inv, a, b); p1h.u[i] = a; p1l.u[i] = b;
        }
        *reinterpret_cast<u64*>(aohi + obase + lg * 4) = p0h.v;
        *reinterpret_cast<u64*>(aolo + obase + lg * 4) = p0l.v;
        *reinterpret_cast<u64*>(aohi + obase + 16 + lg * 4) = p1h.v;
        *reinterpret_cast<u64*>(aolo + obase + 16 + lg * 4) = p1l.v;
    }
}

// ---- fused out-proj + FFN, 32 rows/block, weight frags shared across 2 row-groups ----

__global__ __launch_bounds__(256) void k_outffn(
    const u16* __restrict__ aoh, const u16* __restrict__ aol,
    const u16* __restrict__ awh, const u16* __restrict__ awl,
    const float* __restrict__ ab, const float* __restrict__ hres,
    const float* __restrict__ sc1, const float* __restrict__ sh1,
    const float* __restrict__ h1res,
    const u16* __restrict__ w1h, const u16* __restrict__ w1l,
    const float* __restrict__ b1,
    const u16* __restrict__ w2h, const u16* __restrict__ w2l,
    const float* __restrict__ b2,
    const float* __restrict__ sc2, const float* __restrict__ sh2,
    float* __restrict__ hf, u16* __restrict__ hhi, u16* __restrict__ hlo) {
    __shared__ __align__(16) u16 o_hi[32][136];
    __shared__ __align__(16) u16 o_lo[32][136];
    __shared__ __align__(16) u16 t_hi[32][264];
    __shared__ __align__(16) u16 t_lo[32][264];
    int tid = threadIdx.x;
    int wave = tid >> 6, lane = tid & 63;
    int lr = lane & 15, lg = lane >> 4;
    int r0 = blockIdx.x * 32;
    int cb = wave * 32;
    {
        f32x4 acc[2][2] = {};
        size_t arow0 = (size_t)(r0 + lr) * CHN + lg * 8;
        size_t arow1 = (size_t)(r0 + 16 + lr) * CHN + lg * 8;
        for (int ks = 0; ks < CHN; ks += 32) {
            short8 ah0 = ld_frag(aoh + arow0 + ks);
            short8 al0 = ld_frag(aol + arow0 + ks);
            short8 ah1 = ld_frag(aoh + arow1 + ks);
            short8 al1 = ld_frag(aol + arow1 + ks);
#pragma unroll
            for (int n = 0; n < 2; ++n) {
                size_t wrow = (size_t)(cb + n * 16 + lr) * CHN + ks + lg * 8;
                short8 wh = ld_frag(awh + wrow);
                short8 wl = ld_frag(awl + wrow);
                acc[0][n] = MFMA16(ah0, wh, acc[0][n]);
                acc[0][n] = MFMA16(al0, wh, acc[0][n]);
                acc[0][n] = MFMA16(ah0, wl, acc[0][n]);
                acc[1][n] = MFMA16(ah1, wh, acc[1][n]);
                acc[1][n] = MFMA16(al1, wh, acc[1][n]);
                acc[1][n] = MFMA16(ah1, wl, acc[1][n]);
            }
        }
#pragma unroll
        for (int rg = 0; rg < 2; ++rg)
#pragma unroll
            for (int n = 0; n < 2; ++n) {
                int col = cb + n * 16 + lr;
                float bs = ab[col], sc = sc1[col], sh = sh1[col];
#pragma unroll
                for (int r = 0; r < 4; ++r) {
                    int row = r0 + rg * 16 + lg * 4 + r;
                    int rl = rg * 16 + lg * 4 + r;
                    size_t oidx = (size_t)row * CHN + col;
                    float v = (acc[rg][n][r] + bs + hres[oidx]) * sc + sh + h1res[oidx];
                    u16 hh, ll;
                    fsplit(v, hh, ll);
                    o_hi[rl][col] = hh; o_lo[rl][col] = ll;
                }
            }
    }
    __syncthreads();
    {
        f32x4 acc[2][4] = {};
        int cbB = wave * 64;
        for (int ks = 0; ks < CHN; ks += 32) {
            short8 ah0 = ld_frag(&o_hi[lr][ks + lg * 8]);
            short8 al0 = ld_frag(&o_lo[lr][ks + lg * 8]);
            short8 ah1 = ld_frag(&o_hi[16 + lr][ks + lg * 8]);
            short8 al1 = ld_frag(&o_lo[16 + lr][ks + lg * 8]);
#pragma unroll
            for (int n = 0; n < 4; ++n) {
                size_t wrow = (size_t)(cbB + n * 16 + lr) * CHN + ks + lg * 8;
                short8 wh = ld_frag(w1h + wrow);
                short8 wl = ld_frag(w1l + wrow);
                acc[0][n] = MFMA16(ah0, wh, acc[0][n]);
                acc[0][n] = MFMA16(al0, wh, acc[0][n]);
                acc[0][n] = MFMA16(ah0, wl, acc[0][n]);
                acc[1][n] = MFMA16(ah1, wh, acc[1][n]);
                acc[1][n] = MFMA16(al1, wh, acc[1][n]);
                acc[1][n] = MFMA16(ah1, wl, acc[1][n]);
            }
        }
#pragma unroll
        for (int rg = 0; rg < 2; ++rg)
#pragma unroll
            for (int n = 0; n < 4; ++n) {
                int col = cbB + n * 16 + lr;
                float bs = b1[col];
#pragma unroll
                for (int r = 0; r < 4; ++r) {
                    float v = fmaxf(acc[rg][n][r] + bs, 0.f);
                    u16 hh, ll;
                    fsplit(v, hh, ll);
                    int rl = rg * 16 + lg * 4 + r;
                    t_hi[rl][col] = hh;
                    t_lo[rl][col] = ll;
                }
            }
    }
    __syncthreads();
    {
        f32x4 acc[2][2] = {};
        for (int ks = 0; ks < 2 * CHN; ks += 32) {
            short8 ah0 = ld_frag(&t_hi[lr][ks + lg * 8]);
            short8 al0 = ld_frag(&t_lo[lr][ks + lg * 8]);
            short8 ah1 = ld_frag(&t_hi[16 + lr][ks + lg * 8]);
            short8 al1 = ld_frag(&t_lo[16 + lr][ks + lg * 8]);
#pragma unroll
            for (int n = 0; n < 2; ++n) {
                size_t wrow = (size_t)(cb + n * 16 + lr) * 2 * CHN + ks + lg * 8;
                short8 wh = ld_frag(w2h + wrow);
                short8 wl = ld_frag(w2l + wrow);
                acc[0][n] = MFMA16(ah0, wh, acc[0][n]);
                acc[0][n] = MFMA16(al0, wh, acc[0][n]);
                acc[0][n] = MFMA16(ah0, wl, acc[0][n]);
                acc[1][n] = MFMA16(ah1, wh, acc[1][n]);
                acc[1][n] = MFMA16(al1, wh, acc[1][n]);
                acc[1][n] = MFMA16(ah1, wl, acc[1][n]);
            }
        }
#pragma unroll
        for (int rg = 0; rg < 2; ++rg)
#pragma unroll
            for (int n = 0; n < 2; ++n) {
                int col = cb + n * 16 + lr;
                float bs = b2[col], sc = sc2[col], sh = sh2[col];
#pragma unroll
                for (int r = 0; r < 4; ++r) {
                    int row = r0 + rg * 16 + lg * 4 + r;
                    int rl = rg * 16 + lg * 4 + r;
                    size_t oidx = (size_t)row * CHN + col;
                    float ores = bf2f(o_hi[rl][col]) + bf2f(o_lo[rl][col]);
                    float v = (acc[rg][n][r] + bs + ores) * sc + sh;
                    hf[oidx] = v;
                    u16 hh, ll;
                    fsplit(v, hh, ll);
                    hhi[oidx] = hh; hlo[oidx] = ll;
                }
            }
    }
}

// ---------------- pooling + head MLP ----------------

__global__ __launch_bounds__(128) void k_pool(const float* __restrict__ h,
                                              float* __restrict__ pool) {
    int g = blockIdx.x, sl = blockIdx.y, c = threadIdx.x;
    const float* p = h + ((size_t)g * NPGC + sl * 128) * CHN + c;
    float s = 0.f;
    for (int i = 0; i < 128; ++i) s += p[(size_t)i * CHN];
    atomicAdd(&pool[g * CHN + c], s);
}

__global__ __launch_bounds__(256) void k_head(
    const float* __restrict__ pool, const float* __restrict__ w1,
    const float* __restrict__ b1, const float* __restrict__ w2,
    const float* __restrict__ b2, const float* __restrict__ w3,
    const float* __restrict__ b3, float* __restrict__ out) {
    __shared__ float g1[16][64];
    __shared__ float g2[16][32];
    int t = threadIdx.x;
    for (int idx = t; idx < 16 * 64; idx += 256) {
        int g = idx >> 6, n = idx & 63;
        float s = b1[n];
        for (int k = 0; k < 128; ++k) s += pool[g * 128 + k] * w1[n * 128 + k];
        g1[g][n] = fmaxf(s, 0.f);
    }
    __syncthreads();
    for (int idx = t; idx < 16 * 32; idx += 256) {
        int g = idx >> 5, n = idx & 31;
        float s = b2[n];
        for (int k = 0; k < 64; ++k) s += g1[g][k] * w2[n * 64 + k];
        g2[g][n] = fmaxf(s, 0.f);
    }
    __syncthreads();
    if (t < 16) {
        float s = b3[0];
        for (int k = 0; k < 32; ++k) s += g2[t][k] * w3[k];
        out[t] = s;
    }
}

// ---------------- host ----------------

extern "C" void kernel_launch(void* const* d_in, const int* in_sizes, int n_in,
                              void* d_out, int out_size, void* d_ws, size_t ws_size,
                              hipStream_t stream) {
    (void)in_sizes; (void)n_in; (void)out_size; (void)ws_size;
    const float* x = (const float*)d_in[0];
    const float* edge_attr = (const float*)d_in[1];
    const int* edge_index = (const int*)d_in[2];
    const float* node_w = (const float*)d_in[4];
    const float* node_b = (const float*)d_in[5];
    const float* edge_w = (const float*)d_in[6];
    const float* edge_b = (const float*)d_in[7];
    const float* gine_w1 = (const float*)d_in[8];
    const float* gine_b1 = (const float*)d_in[9];
    const float* gine_w2 = (const float*)d_in[10];
    const float* gine_b2 = (const float*)d_in[11];
    const float* attn_in_w = (const float*)d_in[12];
    const float* attn_in_b = (const float*)d_in[13];
    const float* attn_out_w = (const float*)d_in[14];
    const float* attn_out_b = (const float*)d_in[15];
    const float* mlp_w1 = (const float*)d_in[16];
    const float* mlp_b1 = (const float*)d_in[17];
    const float* mlp_w2 = (const float*)d_in[18];
    const float* mlp_b2 = (const float*)d_in[19];
    const float* bn_g = (const float*)d_in[20];
    const float* bn_bb = (const float*)d_in[21];
    const float* bn_m = (const float*)d_in[22];
    const float* bn_v = (const float*)d_in[23];
    const float* head_w1 = (const float*)d_in[24];
    const float* head_b1 = (const float*)d_in[25];
    const float* head_w2 = (const float*)d_in[26];
    const float* head_b2 = (const float*)d_in[27];
    const float* head_w3 = (const float*)d_in[28];
    const float* head_b3 = (const float*)d_in[29];

    char* ws = (char*)d_ws;
    size_t off = 0;
    auto alloc = [&](size_t bytes) {
        size_t r = off;
        off = (off + bytes + 255) & ~(size_t)255;
        return r;
    };
    const size_t NC = (size_t)NODES * CHN;
    float* h_f32 = (float*)(ws + alloc(NC * 4));
    u16* h_hi = (u16*)(ws + alloc(NC * 2));
    u16* h_lo = (u16*)(ws + alloc(NC * 2));
    u16* x_hi = (u16*)(ws + alloc((size_t)NODES * 64 * 2));
    u16* x_lo = (u16*)(ws + alloc((size_t)NODES * 64 * 2));
    u16* zao_hi = (u16*)(ws + alloc(NC * 2));
    u16* zao_lo = (u16*)(ws + alloc(NC * 2));
    float* h1_f32 = (float*)(ws + alloc(NC * 4));
    u16* q_hi = (u16*)(ws + alloc(NC * 2));
    u16* q_lo = (u16*)(ws + alloc(NC * 2));
    u16* kk_hi = (u16*)(ws + alloc(NC * 2));
    u16* kk_lo = (u16*)(ws + alloc(NC * 2));
    u16* vt_hi = (u16*)(ws + alloc(NC * 2));
    float* pool = (float*)(ws + alloc(NG * CHN * 4));
    u16* node_w_hi = (u16*)(ws + alloc(CHN * 64 * 2));
    u16* node_w_lo = (u16*)(ws + alloc(CHN * 64 * 2));
    u16* gw1_hi = (u16*)(ws + alloc((size_t)NLAYER * CHN * CHN * 2));
    u16* gw1_lo = (u16*)(ws + alloc((size_t)NLAYER * CHN * CHN * 2));
    u16* gw2_hi = (u16*)(ws + alloc((size_t)NLAYER * CHN * CHN * 2));
    u16* gw2_lo = (u16*)(ws + alloc((size_t)NLAYER * CHN * CHN * 2));
    u16* aiw_hi = (u16*)(ws + alloc((size_t)NLAYER * 3 * CHN * CHN * 2));
    u16* aiw_lo = (u16*)(ws + alloc((size_t)NLAYER * 3 * CHN * CHN * 2));
    u16* aow_hi = (u16*)(ws + alloc((size_t)NLAYER * CHN * CHN * 2));
    u16* aow_lo = (u16*)(ws + alloc((size_t)NLAYER * CHN * CHN * 2));
    u16* mw1_hi = (u16*)(ws + alloc((size_t)NLAYER * 2 * CHN * CHN * 2));
    u16* mw1_lo = (u16*)(ws + alloc((size_t)NLAYER * 2 * CHN * CHN * 2));
    u16* mw2_hi = (u16*)(ws + alloc((size_t)NLAYER * 2 * CHN * CHN * 2));
    u16* mw2_lo = (u16*)(ws + alloc((size_t)NLAYER * 2 * CHN * CHN * 2));
    float* bn_scale = (float*)(ws + alloc(NLAYER * 3 * CHN * 4));
    float* bn_shift = (float*)(ws + alloc(NLAYER * 3 * CHN * 4));
    u32* counts = (u32*)(ws + alloc(NODES * 4));
    u32* offsets = (u32*)(ws + alloc((NODES + 1) * 4));
    u32* cursor = (u32*)(ws + alloc(NODES * 4));
    int2* csr_sa = (int2*)(ws + alloc((size_t)NEDGE * 8));

    const int* e_src = edge_index;
    const int* e_dst = edge_index + NEDGE;

    {
        SplitJobs j;
        const float* srcs[8] = {x, node_w, gine_w1, gine_w2, attn_in_w,
                                attn_out_w, mlp_w1, mlp_w2};
        u16* his[8] = {x_hi, node_w_hi, gw1_hi, gw2_hi, aiw_hi, aow_hi, mw1_hi, mw2_hi};
        u16* los[8] = {x_lo, node_w_lo, gw1_lo, gw2_lo, aiw_lo, aow_lo, mw1_lo, mw2_lo};
        int ns[8] = {NODES * 64, CHN * 64, NLAYER * CHN * CHN, NLAYER * CHN * CHN,
                     NLAYER * 3 * CHN * CHN, NLAYER * CHN * CHN,
                     NLAYER * 2 * CHN * CHN, NLAYER * 2 * CHN * CHN};
        int cum = 0;
        for (int i = 0; i < 8; ++i) {
            j.src[i] = srcs[i]; j.hi[i] = his[i]; j.lo[i] = los[i];
            cum += ns[i] / 256;
            j.blk_end[i] = cum;
        }
        k_split8<<<dim3(cum), dim3(256), 0, stream>>>(j);
    }

    k_bnprep<<<dim3((NLAYER * 3 * CHN + 255) / 256), dim3(256), 0, stream>>>(
        bn_g, bn_bb, bn_m, bn_v, bn_scale, bn_shift);

    k_zero_u32<<<dim3(NODES / 256), dim3(256), 0, stream>>>(counts, NODES);
    k_count<<<dim3(NEDGE / 256), dim3(256), 0, stream>>>(e_dst, counts);
    k_scan<<<dim3(1), dim3(256), 0, stream>>>(counts, offsets, cursor);
    k_fill<<<dim3(NEDGE / 256), dim3(256), 0, stream>>>(e_src, e_dst, edge_attr,
                                                        cursor, csr_sa);

    // node projection: h = x @ node_w^T + node_b
    k_gemm<<<dim3(NODES / 64, CHN / 32), dim3(256), 0, stream>>>(
        x_hi, x_lo, node_w_hi, node_w_lo, node_b, h_f32, h_hi, h_lo, 64, CHN);

    for (int l = 0; l < NLAYER; ++l) {
        size_t wo = (size_t)l * CHN * CHN;
        const float* sc0 = bn_scale + (l * 3 + 0) * CHN;
        const float* sh0 = bn_shift + (l * 3 + 0) * CHN;
        const float* sc1 = bn_scale + (l * 3 + 1) * CHN;
        const float* sh1 = bn_shift + (l * 3 + 1) * CHN;
        const float* sc2 = bn_scale + (l * 3 + 2) * CHN;
        const float* sh2 = bn_shift + (l * 3 + 2) * CHN;

        // agg (4096 blocks) ∥ qkv (3072 blocks)
        k_aggqkv<<<dim3(NODES / 4 + 3072), dim3(256), 0, stream>>>(
            h_hi, h_f32, offsets, csr_sa, edge_w, edge_b, zao_hi, zao_lo,
            h_lo, aiw_hi + wo * 3, aiw_lo + wo * 3, attn_in_b + l * 3 * CHN,
            q_hi, q_lo, kk_hi, kk_lo, vt_hi);
        // gine (256 blocks) ∥ attn (512 blocks)
        k_gineattn<<<dim3(NODES / 64 + 512), dim3(256), 0, stream>>>(
            zao_hi, zao_lo, gw1_hi + wo, gw1_lo + wo, gine_b1 + l * CHN,
            gw2_hi + wo, gw2_lo + wo, gine_b2 + l * CHN, h_f32, sc0, sh0, h1_f32,
            q_hi, q_lo, kk_hi, kk_lo, vt_hi, zao_hi, zao_lo);
        // out-proj + FFN
        k_outffn<<<dim3(NODES / 32), dim3(256), 0, stream>>>(
            zao_hi, zao_lo, aow_hi + wo, aow_lo + wo, attn_out_b + l * CHN,
            h_f32, sc1, sh1, h1_f32,
            mw1_hi + wo * 2, mw1_lo + wo * 2, mlp_b1 + l * 2 * CHN,
            mw2_hi + wo * 2, mw2_lo + wo * 2, mlp_b2 + l * CHN, sc2, sh2,
            h_f32, h_hi, h_lo);
    }

    k_zero_u32<<<dim3(NG * CHN / 256), dim3(256), 0, stream>>>((u32*)pool, NG * CHN);
    k_pool<<<dim3(NG, 8), dim3(128), 0, stream>>>(h_f32, pool);
    k_head<<<dim3(1), dim3(256), 0, stream>>>(pool, head_w1, head_b1, head_w2,
                                              head_b2, head_w3, head_b3,
                                              (float*)d_out);
}

// Round 17
// 677.423 us; speedup vs baseline: 1.0538x; 1.0538x over previous
//
#include <hip/hip_runtime.h>
#include <hip/hip_bf16.h>

typedef __attribute__((ext_vector_type(8))) short short8;
typedef __attribute__((ext_vector_type(4))) float f32x4;
typedef __attribute__((ext_vector_type(2))) unsigned int u32x2;
typedef unsigned short u16;
typedef unsigned int u32;
typedef unsigned long long u64;

#define NODES 16384
#define CHN 128
#define NEDGE 524288
#define NG 16
#define NPGC 1024
#define NHEAD 4
#define HDIM 32
#define NLAYER 4
#define CL 0.2550348281f   // log2(e)/sqrt(HDIM), folded into Q at QKV store

#if __has_builtin(__builtin_amdgcn_exp2f)
#define EXP2(x) __builtin_amdgcn_exp2f(x)
#else
#define EXP2(x) exp2f(x)
#endif

__device__ __forceinline__ float bf2f(u16 u) {
    union { u32 u; float f; } c; c.u = ((u32)u) << 16; return c.f;
}
__device__ __forceinline__ u16 f2bf(float f) {
    union { float f; u32 u; } c; c.f = f;
    u32 r = c.u + 0x7fffu + ((c.u >> 16) & 1u);
    return (u16)(r >> 16);
}
__device__ __forceinline__ void fsplit(float f, u16& hi, u16& lo) {
    u16 h = f2bf(f);
    hi = h;
    lo = f2bf(f - bf2f(h));
}
__device__ __forceinline__ u32 cvtpk_bf16(float a, float b) {
    u32 r;
    asm("v_cvt_pk_bf16_f32 %0, %1, %2" : "=v"(r) : "v"(a), "v"(b));
    return r;
}

#define MFMA16(a, b, c) __builtin_amdgcn_mfma_f32_16x16x32_bf16((a), (b), (c), 0, 0, 0)

__device__ __forceinline__ short8 ld_frag(const u16* p) {
    return *reinterpret_cast<const short8*>(p);
}

// ---------------- setup kernels ----------------

struct SplitJobs {
    const float* src[8];
    u16* hi[8];
    u16* lo[8];
    int blk_end[8];
};

__global__ void k_split8(SplitJobs jobs) {
    int b = blockIdx.x;
    int seg = 0;
    while (b >= jobs.blk_end[seg]) ++seg;
    int base = seg ? jobs.blk_end[seg - 1] : 0;
    int i = (b - base) * 256 + threadIdx.x;
    u16 h, l;
    fsplit(jobs.src[seg][i], h, l);
    jobs.hi[seg][i] = h;
    jobs.lo[seg][i] = l;
}

__global__ void k_bnprep(const float* __restrict__ g, const float* __restrict__ b,
                         const float* __restrict__ m, const float* __restrict__ v,
                         float* __restrict__ scale, float* __restrict__ shift) {
    int i = blockIdx.x * 256 + threadIdx.x;
    if (i < NLAYER * 3 * CHN) {
        float s = g[i] * rsqrtf(v[i] + 1e-5f);
        scale[i] = s;
        shift[i] = b[i] - m[i] * s;
    }
}

__global__ void k_zero_u32(u32* __restrict__ p, int n) {
    int i = blockIdx.x * 256 + threadIdx.x;
    if (i < n) p[i] = 0u;
}

__global__ void k_count(const int* __restrict__ dst, u32* __restrict__ counts) {
    int e = blockIdx.x * 256 + threadIdx.x;
    if (e < NEDGE) atomicAdd(&counts[dst[e]], 1u);
}

__global__ void k_scan(const u32* __restrict__ counts, u32* __restrict__ offsets,
                       u32* __restrict__ cursor) {
    __shared__ u32 part[256];
    int t = threadIdx.x;
    int base = t * 64;
    u32 s = 0;
    for (int i = 0; i < 64; ++i) s += counts[base + i];
    part[t] = s;
    __syncthreads();
    for (int off = 1; off < 256; off <<= 1) {
        u32 val = (t >= off) ? part[t - off] : 0u;
        __syncthreads();
        part[t] += val;
        __syncthreads();
    }
    u32 run = (t == 0) ? 0u : part[t - 1];
    for (int i = 0; i < 64; ++i) {
        offsets[base + i] = run;
        cursor[base + i] = run;
        run += counts[base + i];
    }
    if (t == 255) offsets[NODES] = run;
}

// combined (src, attr-bits) 8B store: halves scattered-write line traffic
__global__ void k_fill(const int* __restrict__ src, const int* __restrict__ dst,
                       const float* __restrict__ eattr, u32* __restrict__ cursor,
                       int2* __restrict__ csr_sa) {
    int e = blockIdx.x * 256 + threadIdx.x;
    if (e >= NEDGE) return;
    int d = dst[e];
    u32 p = atomicAdd(&cursor[d], 1u);
    csr_sa[p] = make_int2(src[e], __float_as_int(eattr[e]));
}

// ---- FAT kernel 1: GINE aggregation (blocks < NODES/4) ∥ QKV GEMM (rest) ----
// agg: 8-wide unrolled gather pipeline (8 independent h-row loads in flight).

__global__ __launch_bounds__(256) void k_aggqkv(
    // agg args
    const u16* __restrict__ h_hi, const float* __restrict__ h_f32,
    const u32* __restrict__ offsets, const int2* __restrict__ csr_sa,
    const float* __restrict__ ew, const float* __restrict__ eb,
    u16* __restrict__ z_hi, u16* __restrict__ z_lo,
    // qkv args
    const u16* __restrict__ h_lo, const u16* __restrict__ Whi,
    const u16* __restrict__ Wlo, const float* __restrict__ bias,
    u16* __restrict__ q_hi, u16* __restrict__ q_lo,
    u16* __restrict__ k_hi, u16* __restrict__ k_lo,
    u16* __restrict__ vt_hi) {
    int tid = threadIdx.x;
    int wave = tid >> 6, lane = tid & 63;
    if (blockIdx.x < NODES / 4) {
        // ---- aggregation: 4 nodes/block, one wave per node, 2 channels/lane ----
        int node = blockIdx.x * 4 + wave;
        int c0 = lane * 2;
        float w0 = ew[c0], w1 = ew[c0 + 1];
        float b0 = eb[c0], b1 = eb[c0 + 1];
        u32 beg = offsets[node], end = offsets[node + 1];
        float acc0 = 0.f, acc1 = 0.f;
        u32 i = beg;
        // 8-wide unrolled main loop: 8 independent gathers in flight
        for (; i + 8 <= end; i += 8) {
            int2 es[8];
            u32 us[8];
#pragma unroll
            for (int j = 0; j < 8; ++j) es[j] = csr_sa[i + j];
#pragma unroll
            for (int j = 0; j < 8; ++j)
                us[j] = *reinterpret_cast<const u32*>(
                    h_hi + (size_t)es[j].x * CHN + c0);
#pragma unroll
            for (int j = 0; j < 8; ++j) {
                float a = __int_as_float(es[j].y);
                float f0 = bf2f((u16)(us[j] & 0xffffu));
                float f1 = bf2f((u16)(us[j] >> 16));
                acc0 += fmaxf(f0 + a * w0 + b0, 0.f);
                acc1 += fmaxf(f1 + a * w1 + b1, 0.f);
            }
        }
        for (; i < end; ++i) {
            int2 e = csr_sa[i];
            u32 u = *reinterpret_cast<const u32*>(h_hi + (size_t)e.x * CHN + c0);
            float a = __int_as_float(e.y);
            float f0 = bf2f((u16)(u & 0xffffu));
            float f1 = bf2f((u16)(u >> 16));
            acc0 += fmaxf(f0 + a * w0 + b0, 0.f);
            acc1 += fmaxf(f1 + a * w1 + b1, 0.f);
        }
        size_t idx = (size_t)node * CHN + c0;
        float z0 = h_f32[idx] + acc0;
        float z1v = h_f32[idx + 1] + acc1;
        u16 h, l;
        fsplit(z0, h, l); z_hi[idx] = h; z_lo[idx] = l;
        fsplit(z1v, h, l); z_hi[idx + 1] = h; z_lo[idx + 1] = l;
        return;
    }
    // ---- QKV GEMM; Q pre-scaled by CL ----
    const int K = 128;
    int id = blockIdx.x - NODES / 4;
    int bx = id & 255, ny = id >> 8;
    int lr = lane & 15, lg = lane >> 4;
    int r0 = bx * 64 + wave * 16;
    int nb = ny * 32;
    f32x4 acc[2] = {};
    size_t arow = (size_t)(r0 + lr) * K + lg * 8;
    for (int ks = 0; ks < K; ks += 32) {
        short8 ah = ld_frag(h_hi + arow + ks);
        short8 al = ld_frag(h_lo + arow + ks);
#pragma unroll
        for (int n = 0; n < 2; ++n) {
            size_t wrow = (size_t)(nb + n * 16 + lr) * K + ks + lg * 8;
            short8 wh = ld_frag(Whi + wrow);
            short8 wl = ld_frag(Wlo + wrow);
            acc[n] = MFMA16(ah, wh, acc[n]);
            acc[n] = MFMA16(al, wh, acc[n]);
            acc[n] = MFMA16(ah, wl, acc[n]);
        }
    }
#pragma unroll
    for (int n = 0; n < 2; ++n) {
        int col = nb + n * 16 + lr;
        int region = col >> 7;
        int c = col & 127;
        int hh = c >> 5, d = c & 31;
        float bs = bias[col];
#pragma unroll
        for (int r = 0; r < 4; ++r) {
            int row = r0 + lg * 4 + r;
            float v = acc[n][r] + bs;
            int g = row >> 10, p = row & 1023;
            size_t gh = (size_t)(g * NHEAD + hh);
            if (region == 0) {
                u16 vh, vl;
                fsplit(v * CL, vh, vl);
                size_t o = (gh * NPGC + p) * HDIM + d;
                q_hi[o] = vh; q_lo[o] = vl;
            } else if (region == 1) {
                u16 vh, vl;
                fsplit(v, vh, vl);
                size_t o = (gh * NPGC + p) * HDIM + d;
                k_hi[o] = vh; k_lo[o] = vl;
            } else {
                vt_hi[(gh * HDIM + d) * NPGC + p] = f2bf(v);
            }
        }
    }
}

// ------ split GEMM (16x32 wave tile) — used for node projection ------

__global__ __launch_bounds__(256) void k_gemm(
    const u16* __restrict__ Ahi, const u16* __restrict__ Alo,
    const u16* __restrict__ Whi, const u16* __restrict__ Wlo,
    const float* __restrict__ bias, float* __restrict__ out_f32,
    u16* __restrict__ out_hi, u16* __restrict__ out_lo, int K, int Nc) {
    int tid = threadIdx.x;
    int wave = tid >> 6, lane = tid & 63;
    int lr = lane & 15, lg = lane >> 4;
    int r0 = blockIdx.x * 64 + wave * 16;
    int nb = blockIdx.y * 32;
    f32x4 acc[2] = {};
    size_t arow = (size_t)(r0 + lr) * K + lg * 8;
    for (int ks = 0; ks < K; ks += 32) {
        short8 ah = ld_frag(Ahi + arow + ks);
        short8 al = ld_frag(Alo + arow + ks);
#pragma unroll
        for (int n = 0; n < 2; ++n) {
            size_t wrow = (size_t)(nb + n * 16 + lr) * K + ks + lg * 8;
            short8 wh = ld_frag(Whi + wrow);
            short8 wl = ld_frag(Wlo + wrow);
            acc[n] = MFMA16(ah, wh, acc[n]);
            acc[n] = MFMA16(al, wh, acc[n]);
            acc[n] = MFMA16(ah, wl, acc[n]);
        }
    }
#pragma unroll
    for (int n = 0; n < 2; ++n) {
        int col = nb + n * 16 + lr;
        float bs = bias[col];
#pragma unroll
        for (int r = 0; r < 4; ++r) {
            int row = r0 + lg * 4 + r;
            size_t oidx = (size_t)row * Nc + col;
            float v = acc[n][r] + bs;
            out_f32[oidx] = v;
            u16 hh, ll;
            fsplit(v, hh, ll);
            out_hi[oidx] = hh; out_lo[oidx] = ll;
        }
    }
}

// ---- FAT kernel 2: fused GINE MLP (blocks < 256) ∥ flash attention (rest) ----
// gine: 64 rows/block, 4 row-groups/wave (12 MFMA per weight-pair load).

__global__ __launch_bounds__(256) void k_gineattn(
    // gine args
    const u16* __restrict__ zhi, const u16* __restrict__ zlo,
    const u16* __restrict__ w1hi, const u16* __restrict__ w1lo,
    const float* __restrict__ b1,
    const u16* __restrict__ w2hi, const u16* __restrict__ w2lo,
    const float* __restrict__ b2, const float* __restrict__ resid,
    const float* __restrict__ bnsc, const float* __restrict__ bnsh,
    float* __restrict__ h1out,
    // attn args
    const u16* __restrict__ qhi, const u16* __restrict__ qlo,
    const u16* __restrict__ khi, const u16* __restrict__ klo,
    const u16* __restrict__ vthi,
    u16* __restrict__ aohi, u16* __restrict__ aolo) {
    __shared__ __align__(16) u16 smem[128][136];   // gine: t_hi rows 0-63, t_lo rows 64-127
    int tid = threadIdx.x;
    int wave = tid >> 6, lane = tid & 63;
    int lr = lane & 15, lg = lane >> 4;
    if (blockIdx.x < NODES / 64) {
        // ---------------- GINE MLP: 64 rows/block, 4 row-groups/wave ----------------
        int r0 = blockIdx.x * 64;
        int cb = wave * 32;
        {
            f32x4 acc[4][2] = {};
            for (int ks = 0; ks < CHN; ks += 32) {
                short8 ah[4], al[4];
#pragma unroll
                for (int rg = 0; rg < 4; ++rg) {
                    size_t arow = (size_t)(r0 + rg * 16 + lr) * CHN + ks + lg * 8;
                    ah[rg] = ld_frag(zhi + arow);
                    al[rg] = ld_frag(zlo + arow);
                }
#pragma unroll
                for (int n = 0; n < 2; ++n) {
                    size_t wrow = (size_t)(cb + n * 16 + lr) * CHN + ks + lg * 8;
                    short8 wh = ld_frag(w1hi + wrow);
                    short8 wl = ld_frag(w1lo + wrow);
#pragma unroll
                    for (int rg = 0; rg < 4; ++rg) {
                        acc[rg][n] = MFMA16(ah[rg], wh, acc[rg][n]);
                        acc[rg][n] = MFMA16(al[rg], wh, acc[rg][n]);
                        acc[rg][n] = MFMA16(ah[rg], wl, acc[rg][n]);
                    }
                }
            }
#pragma unroll
            for (int rg = 0; rg < 4; ++rg)
#pragma unroll
                for (int n = 0; n < 2; ++n) {
                    int col = cb + n * 16 + lr;
                    float bs = b1[col];
#pragma unroll
                    for (int r = 0; r < 4; ++r) {
                        float v = fmaxf(acc[rg][n][r] + bs, 0.f);
                        u16 hh, ll;
                        fsplit(v, hh, ll);
                        int rl = rg * 16 + lg * 4 + r;
                        smem[rl][col] = hh;
                        smem[64 + rl][col] = ll;
                    }
                }
        }
        __syncthreads();
        {
            f32x4 acc[4][2] = {};
            for (int ks = 0; ks < CHN; ks += 32) {
                short8 ah[4], al[4];
#pragma unroll
                for (int rg = 0; rg < 4; ++rg) {
                    ah[rg] = ld_frag(&smem[rg * 16 + lr][ks + lg * 8]);
                    al[rg] = ld_frag(&smem[64 + rg * 16 + lr][ks + lg * 8]);
                }
#pragma unroll
                for (int n = 0; n < 2; ++n) {
                    size_t wrow = (size_t)(cb + n * 16 + lr) * CHN + ks + lg * 8;
                    short8 wh = ld_frag(w2hi + wrow);
                    short8 wl = ld_frag(w2lo + wrow);
#pragma unroll
                    for (int rg = 0; rg < 4; ++rg) {
                        acc[rg][n] = MFMA16(ah[rg], wh, acc[rg][n]);
                        acc[rg][n] = MFMA16(al[rg], wh, acc[rg][n]);
                        acc[rg][n] = MFMA16(ah[rg], wl, acc[rg][n]);
                    }
                }
            }
#pragma unroll
            for (int rg = 0; rg < 4; ++rg)
#pragma unroll
                for (int n = 0; n < 2; ++n) {
                    int col = cb + n * 16 + lr;
                    float bs = b2[col], sc = bnsc[col], sh = bnsh[col];
#pragma unroll
                    for (int r = 0; r < 4; ++r) {
                        int row = r0 + rg * 16 + lg * 4 + r;
                        size_t oidx = (size_t)row * CHN + col;
                        float v = acc[rg][n][r] + bs + resid[oidx];
                        h1out[oidx] = v * sc + sh;
                    }
                }
        }
        return;
    }
    // ---------------- attention: swapped QK^T, dual-stream, defer-max ----------------
    int id = blockIdx.x - NODES / 64;
    int gh = id & 63;           // id%8==gh%8 -> per-gh XCD locality (256 offset %8==0)
    int bx = id >> 6;           // 0..7
    int qA = bx * 128 + wave * 32;
    int qB = qA + 16;
    size_t base = (size_t)gh * NPGC * HDIM;
    size_t vbase = (size_t)gh * HDIM * NPGC;
    short8 qhA = ld_frag(qhi + base + (size_t)(qA + lr) * HDIM + lg * 8);
    short8 qlA = ld_frag(qlo + base + (size_t)(qA + lr) * HDIM + lg * 8);
    short8 qhB = ld_frag(qhi + base + (size_t)(qB + lr) * HDIM + lg * 8);
    short8 qlB = ld_frag(qlo + base + (size_t)(qB + lr) * HDIM + lg * 8);
    const u16* Kh = khi + base;
    const u16* Kl = klo + base;
    const u16* Vh = vthi + vbase;
    f32x4 o0A = {}, o1A = {}, o0B = {}, o1B = {};
    f32x4 lsA = {}, lsB = {};
    float mA = -1e30f, mB = -1e30f;
    const f32x4 zero = {};
    u16 (*plds)[136] = (u16 (*)[136])&smem[wave * 16][0];
    for (int kv = 0; kv < NPGC; kv += 128) {
        f32x4 sA[8], sB[8];
        __builtin_amdgcn_s_setprio(1);
#pragma unroll
        for (int f = 0; f < 8; ++f) {
            size_t kr = (size_t)(kv + f * 16 + lr) * HDIM + lg * 8;
            short8 kh = ld_frag(Kh + kr);
            short8 kl2 = ld_frag(Kl + kr);
            sA[f] = MFMA16(kh, qlA, MFMA16(kl2, qhA, MFMA16(kh, qhA, zero)));
            sB[f] = MFMA16(kh, qlB, MFMA16(kl2, qhB, MFMA16(kh, qhB, zero)));
        }
        __builtin_amdgcn_s_setprio(0);
        // softmax A: defer-max fast path
        {
            f32x4 mm = sA[0];
#pragma unroll
            for (int f = 1; f < 8; ++f)
#pragma unroll
                for (int i = 0; i < 4; ++i) mm[i] = fmaxf(mm[i], sA[f][i]);
            float mx = fmaxf(fmaxf(mm[0], mm[1]), fmaxf(mm[2], mm[3]));
            if (!__all(mx <= mA + 8.f)) {
                mx = fmaxf(mx, __shfl_xor(mx, 16));
                mx = fmaxf(mx, __shfl_xor(mx, 32));
                float mn = fmaxf(mA, mx);
                float corr = EXP2(mA - mn);
                mA = mn;
#pragma unroll
                for (int i = 0; i < 4; ++i) {
                    lsA[i] *= corr;
                    o0A[i] *= corr; o1A[i] *= corr;
                }
            }
#pragma unroll
            for (int f = 0; f < 8; ++f)
#pragma unroll
                for (int i = 0; i < 4; ++i) sA[f][i] = EXP2(sA[f][i] - mA);
            f32x4 s4 = sA[0];
#pragma unroll
            for (int f = 1; f < 8; ++f)
#pragma unroll
                for (int i = 0; i < 4; ++i) s4[i] += sA[f][i];
            lsA += s4;
#pragma unroll
            for (int f = 0; f < 8; ++f) {
                u32x2 wv;
                wv[0] = cvtpk_bf16(sA[f][0], sA[f][1]);
                wv[1] = cvtpk_bf16(sA[f][2], sA[f][3]);
                *reinterpret_cast<u32x2*>(&plds[lr][f * 16 + lg * 4]) = wv;
            }
        }
        // PV A (V frags kept for B)
        short8 vs0[4], vs1[4];
        __builtin_amdgcn_s_setprio(1);
#pragma unroll
        for (int kk = 0; kk < 4; ++kk) {
            short8 pf = ld_frag(&plds[lr][kk * 32 + lg * 8]);
            vs0[kk] = ld_frag(Vh + (size_t)lr * NPGC + kv + kk * 32 + lg * 8);
            vs1[kk] = ld_frag(Vh + (size_t)(16 + lr) * NPGC + kv + kk * 32 + lg * 8);
            o0A = MFMA16(vs0[kk], pf, o0A);
            o1A = MFMA16(vs1[kk], pf, o1A);
        }
        __builtin_amdgcn_s_setprio(0);
        // softmax B
        {
            f32x4 mm = sB[0];
#pragma unroll
            for (int f = 1; f < 8; ++f)
#pragma unroll
                for (int i = 0; i < 4; ++i) mm[i] = fmaxf(mm[i], sB[f][i]);
            float mx = fmaxf(fmaxf(mm[0], mm[1]), fmaxf(mm[2], mm[3]));
            if (!__all(mx <= mB + 8.f)) {
                mx = fmaxf(mx, __shfl_xor(mx, 16));
                mx = fmaxf(mx, __shfl_xor(mx, 32));
                float mn = fmaxf(mB, mx);
                float corr = EXP2(mB - mn);
                mB = mn;
#pragma unroll
                for (int i = 0; i < 4; ++i) {
                    lsB[i] *= corr;
                    o0B[i] *= corr; o1B[i] *= corr;
                }
            }
#pragma unroll
            for (int f = 0; f < 8; ++f)
#pragma unroll
                for (int i = 0; i < 4; ++i) sB[f][i] = EXP2(sB[f][i] - mB);
            f32x4 s4 = sB[0];
#pragma unroll
            for (int f = 1; f < 8; ++f)
#pragma unroll
                for (int i = 0; i < 4; ++i) s4[i] += sB[f][i];
            lsB += s4;
#pragma unroll
            for (int f = 0; f < 8; ++f) {
                u32x2 wv;
                wv[0] = cvtpk_bf16(sB[f][0], sB[f][1]);
                wv[1] = cvtpk_bf16(sB[f][2], sB[f][3]);
                *reinterpret_cast<u32x2*>(&plds[lr][f * 16 + lg * 4]) = wv;
            }
        }
        // PV B
        __builtin_amdgcn_s_setprio(1);
#pragma unroll
        for (int kk = 0; kk < 4; ++kk) {
            short8 pf = ld_frag(&plds[lr][kk * 32 + lg * 8]);
            o0B = MFMA16(vs0[kk], pf, o0B);
            o1B = MFMA16(vs1[kk], pf, o1B);
        }
        __builtin_amdgcn_s_setprio(0);
    }
    float lA = (lsA[0] + lsA[1]) + (lsA[2] + lsA[3]);
    lA += __shfl_xor(lA, 16);
    lA += __shfl_xor(lA, 32);
    float lB = (lsB[0] + lsB[1]) + (lsB[2] + lsB[3]);
    lB += __shfl_xor(lB, 16);
    lB += __shfl_xor(lB, 32);
    int g = gh >> 2, hh = gh & 3;
    {
        float inv = 1.f / lA;
        size_t obase = ((size_t)g * NPGC + qA + lr) * CHN + hh * HDIM;
        union { u16 u[4]; u64 v; } p0h, p0l, p1h, p1l;
#pragma unroll
        for (int i = 0; i < 4; ++i) {
            u16 a, b;
            fsplit(o0A[i] * inv, a, b); p0h.u[i] = a; p0l.u[i] = b;
            fsplit(o1A[i] * inv, a, b); p1h.u[i] = a; p1l.u[i] = b;
        }
        *reinterpret_cast<u64*>(aohi + obase + lg * 4) = p0h.v;
        *reinterpret_cast<u64*>(aolo + obase + lg * 4) = p0l.v;
        *reinterpret_cast<u64*>(aohi + obase + 16 + lg * 4) = p1h.v;
        *reinterpret_cast<u64*>(aolo + obase + 16 + lg * 4) = p1l.v;
    }
    {
        float inv = 1.f / lB;
        size_t obase = ((size_t)g * NPGC + qB + lr) * CHN + hh * HDIM;
        union { u16 u[4]; u64 v; } p0h, p0l, p1h, p1l;
#pragma unroll
        for (int i = 0; i < 4; ++i) {
            u16 a, b;
            fsplit(o0B[i] * inv, a, b); p0h.u[i] = a; p0l.u[i] = b;
            fsplit(o1B[i] * inv, a, b); p1h.u[i] = a; p1l.u[i] = b;
        }
        *reinterpret_cast<u64*>(aohi + obase + lg * 4) = p0h.v;
        *reinterpret_cast<u64*>(aolo + obase + lg * 4) = p0l.v;
        *reinterpret_cast<u64*>(aohi + obase + 16 + lg * 4) = p1h.v;
        *reinterpret_cast<u64*>(aolo + obase + 16 + lg * 4) = p1l.v;
    }
}

// ---- fused out-proj + FFN, 32 rows/block, weight frags shared across 2 row-groups ----

__global__ __launch_bounds__(256) void k_outffn(
    const u16* __restrict__ aoh, const u16* __restrict__ aol,
    const u16* __restrict__ awh, const u16* __restrict__ awl,
    const float* __restrict__ ab, const float* __restrict__ hres,
    const float* __restrict__ sc1, const float* __restrict__ sh1,
    const float* __restrict__ h1res,
    const u16* __restrict__ w1h, const u16* __restrict__ w1l,
    const float* __restrict__ b1,
    const u16* __restrict__ w2h, const u16* __restrict__ w2l,
    const float* __restrict__ b2,
    const float* __restrict__ sc2, const float* __restrict__ sh2,
    float* __restrict__ hf, u16* __restrict__ hhi, u16* __restrict__ hlo) {
    __shared__ __align__(16) u16 o_hi[32][136];
    __shared__ __align__(16) u16 o_lo[32][136];
    __shared__ __align__(16) u16 t_hi[32][264];
    __shared__ __align__(16) u16 t_lo[32][264];
    int tid = threadIdx.x;
    int wave = tid >> 6, lane = tid & 63;
    int lr = lane & 15, lg = lane >> 4;
    int r0 = blockIdx.x * 32;
    int cb = wave * 32;
    {
        f32x4 acc[2][2] = {};
        size_t arow0 = (size_t)(r0 + lr) * CHN + lg * 8;
        size_t arow1 = (size_t)(r0 + 16 + lr) * CHN + lg * 8;
        for (int ks = 0; ks < CHN; ks += 32) {
            short8 ah0 = ld_frag(aoh + arow0 + ks);
            short8 al0 = ld_frag(aol + arow0 + ks);
            short8 ah1 = ld_frag(aoh + arow1 + ks);
            short8 al1 = ld_frag(aol + arow1 + ks);
#pragma unroll
            for (int n = 0; n < 2; ++n) {
                size_t wrow = (size_t)(cb + n * 16 + lr) * CHN + ks + lg * 8;
                short8 wh = ld_frag(awh + wrow);
                short8 wl = ld_frag(awl + wrow);
                acc[0][n] = MFMA16(ah0, wh, acc[0][n]);
                acc[0][n] = MFMA16(al0, wh, acc[0][n]);
                acc[0][n] = MFMA16(ah0, wl, acc[0][n]);
                acc[1][n] = MFMA16(ah1, wh, acc[1][n]);
                acc[1][n] = MFMA16(al1, wh, acc[1][n]);
                acc[1][n] = MFMA16(ah1, wl, acc[1][n]);
            }
        }
#pragma unroll
        for (int rg = 0; rg < 2; ++rg)
#pragma unroll
            for (int n = 0; n < 2; ++n) {
                int col = cb + n * 16 + lr;
                float bs = ab[col], sc = sc1[col], sh = sh1[col];
#pragma unroll
                for (int r = 0; r < 4; ++r) {
                    int row = r0 + rg * 16 + lg * 4 + r;
                    int rl = rg * 16 + lg * 4 + r;
                    size_t oidx = (size_t)row * CHN + col;
                    float v = (acc[rg][n][r] + bs + hres[oidx]) * sc + sh + h1res[oidx];
                    u16 hh, ll;
                    fsplit(v, hh, ll);
                    o_hi[rl][col] = hh; o_lo[rl][col] = ll;
                }
            }
    }
    __syncthreads();
    {
        f32x4 acc[2][4] = {};
        int cbB = wave * 64;
        for (int ks = 0; ks < CHN; ks += 32) {
            short8 ah0 = ld_frag(&o_hi[lr][ks + lg * 8]);
            short8 al0 = ld_frag(&o_lo[lr][ks + lg * 8]);
            short8 ah1 = ld_frag(&o_hi[16 + lr][ks + lg * 8]);
            short8 al1 = ld_frag(&o_lo[16 + lr][ks + lg * 8]);
#pragma unroll
            for (int n = 0; n < 4; ++n) {
                size_t wrow = (size_t)(cbB + n * 16 + lr) * CHN + ks + lg * 8;
                short8 wh = ld_frag(w1h + wrow);
                short8 wl = ld_frag(w1l + wrow);
                acc[0][n] = MFMA16(ah0, wh, acc[0][n]);
                acc[0][n] = MFMA16(al0, wh, acc[0][n]);
                acc[0][n] = MFMA16(ah0, wl, acc[0][n]);
                acc[1][n] = MFMA16(ah1, wh, acc[1][n]);
                acc[1][n] = MFMA16(al1, wh, acc[1][n]);
                acc[1][n] = MFMA16(ah1, wl, acc[1][n]);
            }
        }
#pragma unroll
        for (int rg = 0; rg < 2; ++rg)
#pragma unroll
            for (int n = 0; n < 4; ++n) {
                int col = cbB + n * 16 + lr;
                float bs = b1[col];
#pragma unroll
                for (int r = 0; r < 4; ++r) {
                    float v = fmaxf(acc[rg][n][r] + bs, 0.f);
                    u16 hh, ll;
                    fsplit(v, hh, ll);
                    int rl = rg * 16 + lg * 4 + r;
                    t_hi[rl][col] = hh;
                    t_lo[rl][col] = ll;
                }
            }
    }
    __syncthreads();
    {
        f32x4 acc[2][2] = {};
        for (int ks = 0; ks < 2 * CHN; ks += 32) {
            short8 ah0 = ld_frag(&t_hi[lr][ks + lg * 8]);
            short8 al0 = ld_frag(&t_lo[lr][ks + lg * 8]);
            short8 ah1 = ld_frag(&t_hi[16 + lr][ks + lg * 8]);
            short8 al1 = ld_frag(&t_lo[16 + lr][ks + lg * 8]);
#pragma unroll
            for (int n = 0; n < 2; ++n) {
                size_t wrow = (size_t)(cb + n * 16 + lr) * 2 * CHN + ks + lg * 8;
                short8 wh = ld_frag(w2h + wrow);
                short8 wl = ld_frag(w2l + wrow);
                acc[0][n] = MFMA16(ah0, wh, acc[0][n]);
                acc[0][n] = MFMA16(al0, wh, acc[0][n]);
                acc[0][n] = MFMA16(ah0, wl, acc[0][n]);
                acc[1][n] = MFMA16(ah1, wh, acc[1][n]);
                acc[1][n] = MFMA16(al1, wh, acc[1][n]);
                acc[1][n] = MFMA16(ah1, wl, acc[1][n]);
            }
        }
#pragma unroll
        for (int rg = 0; rg < 2; ++rg)
#pragma unroll
            for (int n = 0; n < 2; ++n) {
                int col = cb + n * 16 + lr;
                float bs = b2[col], sc = sc2[col], sh = sh2[col];
#pragma unroll
                for (int r = 0; r < 4; ++r) {
                    int row = r0 + rg * 16 + lg * 4 + r;
                    int rl = rg * 16 + lg * 4 + r;
                    size_t oidx = (size_t)row * CHN + col;
                    float ores = bf2f(o_hi[rl][col]) + bf2f(o_lo[rl][col]);
                    float v = (acc[rg][n][r] + bs + ores) * sc + sh;
                    hf[oidx] = v;
                    u16 hh, ll;
                    fsplit(v, hh, ll);
                    hhi[oidx] = hh; hlo[oidx] = ll;
                }
            }
    }
}

// ---------------- pooling + head MLP ----------------

__global__ __launch_bounds__(128) void k_pool(const float* __restrict__ h,
                                              float* __restrict__ pool) {
    int g = blockIdx.x, sl = blockIdx.y, c = threadIdx.x;
    const float* p = h + ((size_t)g * NPGC + sl * 128) * CHN + c;
    float s = 0.f;
    for (int i = 0; i < 128; ++i) s += p[(size_t)i * CHN];
    atomicAdd(&pool[g * CHN + c], s);
}

__global__ __launch_bounds__(256) void k_head(
    const float* __restrict__ pool, const float* __restrict__ w1,
    const float* __restrict__ b1, const float* __restrict__ w2,
    const float* __restrict__ b2, const float* __restrict__ w3,
    const float* __restrict__ b3, float* __restrict__ out) {
    __shared__ float g1[16][64];
    __shared__ float g2[16][32];
    int t = threadIdx.x;
    for (int idx = t; idx < 16 * 64; idx += 256) {
        int g = idx >> 6, n = idx & 63;
        float s = b1[n];
        for (int k = 0; k < 128; ++k) s += pool[g * 128 + k] * w1[n * 128 + k];
        g1[g][n] = fmaxf(s, 0.f);
    }
    __syncthreads();
    for (int idx = t; idx < 16 * 32; idx += 256) {
        int g = idx >> 5, n = idx & 31;
        float s = b2[n];
        for (int k = 0; k < 64; ++k) s += g1[g][k] * w2[n * 64 + k];
        g2[g][n] = fmaxf(s, 0.f);
    }
    __syncthreads();
    if (t < 16) {
        float s = b3[0];
        for (int k = 0; k < 32; ++k) s += g2[t][k] * w3[k];
        out[t] = s;
    }
}

// ---------------- host ----------------

extern "C" void kernel_launch(void* const* d_in, const int* in_sizes, int n_in,
                              void* d_out, int out_size, void* d_ws, size_t ws_size,
                              hipStream_t stream) {
    (void)in_sizes; (void)n_in; (void)out_size; (void)ws_size;
    const float* x = (const float*)d_in[0];
    const float* edge_attr = (const float*)d_in[1];
    const int* edge_index = (const int*)d_in[2];
    const float* node_w = (const float*)d_in[4];
    const float* node_b = (const float*)d_in[5];
    const float* edge_w = (const float*)d_in[6];
    const float* edge_b = (const float*)d_in[7];
    const float* gine_w1 = (const float*)d_in[8];
    const float* gine_b1 = (const float*)d_in[9];
    const float* gine_w2 = (const float*)d_in[10];
    const float* gine_b2 = (const float*)d_in[11];
    const float* attn_in_w = (const float*)d_in[12];
    const float* attn_in_b = (const float*)d_in[13];
    const float* attn_out_w = (const float*)d_in[14];
    const float* attn_out_b = (const float*)d_in[15];
    const float* mlp_w1 = (const float*)d_in[16];
    const float* mlp_b1 = (const float*)d_in[17];
    const float* mlp_w2 = (const float*)d_in[18];
    const float* mlp_b2 = (const float*)d_in[19];
    const float* bn_g = (const float*)d_in[20];
    const float* bn_bb = (const float*)d_in[21];
    const float* bn_m = (const float*)d_in[22];
    const float* bn_v = (const float*)d_in[23];
    const float* head_w1 = (const float*)d_in[24];
    const float* head_b1 = (const float*)d_in[25];
    const float* head_w2 = (const float*)d_in[26];
    const float* head_b2 = (const float*)d_in[27];
    const float* head_w3 = (const float*)d_in[28];
    const float* head_b3 = (const float*)d_in[29];

    char* ws = (char*)d_ws;
    size_t off = 0;
    auto alloc = [&](size_t bytes) {
        size_t r = off;
        off = (off + bytes + 255) & ~(size_t)255;
        return r;
    };
    const size_t NC = (size_t)NODES * CHN;
    float* h_f32 = (float*)(ws + alloc(NC * 4));
    u16* h_hi = (u16*)(ws + alloc(NC * 2));
    u16* h_lo = (u16*)(ws + alloc(NC * 2));
    u16* x_hi = (u16*)(ws + alloc((size_t)NODES * 64 * 2));
    u16* x_lo = (u16*)(ws + alloc((size_t)NODES * 64 * 2));
    u16* zao_hi = (u16*)(ws + alloc(NC * 2));
    u16* zao_lo = (u16*)(ws + alloc(NC * 2));
    float* h1_f32 = (float*)(ws + alloc(NC * 4));
    u16* q_hi = (u16*)(ws + alloc(NC * 2));
    u16* q_lo = (u16*)(ws + alloc(NC * 2));
    u16* kk_hi = (u16*)(ws + alloc(NC * 2));
    u16* kk_lo = (u16*)(ws + alloc(NC * 2));
    u16* vt_hi = (u16*)(ws + alloc(NC * 2));
    float* pool = (float*)(ws + alloc(NG * CHN * 4));
    u16* node_w_hi = (u16*)(ws + alloc(CHN * 64 * 2));
    u16* node_w_lo = (u16*)(ws + alloc(CHN * 64 * 2));
    u16* gw1_hi = (u16*)(ws + alloc((size_t)NLAYER * CHN * CHN * 2));
    u16* gw1_lo = (u16*)(ws + alloc((size_t)NLAYER * CHN * CHN * 2));
    u16* gw2_hi = (u16*)(ws + alloc((size_t)NLAYER * CHN * CHN * 2));
    u16* gw2_lo = (u16*)(ws + alloc((size_t)NLAYER * CHN * CHN * 2));
    u16* aiw_hi = (u16*)(ws + alloc((size_t)NLAYER * 3 * CHN * CHN * 2));
    u16* aiw_lo = (u16*)(ws + alloc((size_t)NLAYER * 3 * CHN * CHN * 2));
    u16* aow_hi = (u16*)(ws + alloc((size_t)NLAYER * CHN * CHN * 2));
    u16* aow_lo = (u16*)(ws + alloc((size_t)NLAYER * CHN * CHN * 2));
    u16* mw1_hi = (u16*)(ws + alloc((size_t)NLAYER * 2 * CHN * CHN * 2));
    u16* mw1_lo = (u16*)(ws + alloc((size_t)NLAYER * 2 * CHN * CHN * 2));
    u16* mw2_hi = (u16*)(ws + alloc((size_t)NLAYER * 2 * CHN * CHN * 2));
    u16* mw2_lo = (u16*)(ws + alloc((size_t)NLAYER * 2 * CHN * CHN * 2));
    float* bn_scale = (float*)(ws + alloc(NLAYER * 3 * CHN * 4));
    float* bn_shift = (float*)(ws + alloc(NLAYER * 3 * CHN * 4));
    u32* counts = (u32*)(ws + alloc(NODES * 4));
    u32* offsets = (u32*)(ws + alloc((NODES + 1) * 4));
    u32* cursor = (u32*)(ws + alloc(NODES * 4));
    int2* csr_sa = (int2*)(ws + alloc((size_t)NEDGE * 8));

    const int* e_src = edge_index;
    const int* e_dst = edge_index + NEDGE;

    {
        SplitJobs j;
        const float* srcs[8] = {x, node_w, gine_w1, gine_w2, attn_in_w,
                                attn_out_w, mlp_w1, mlp_w2};
        u16* his[8] = {x_hi, node_w_hi, gw1_hi, gw2_hi, aiw_hi, aow_hi, mw1_hi, mw2_hi};
        u16* los[8] = {x_lo, node_w_lo, gw1_lo, gw2_lo, aiw_lo, aow_lo, mw1_lo, mw2_lo};
        int ns[8] = {NODES * 64, CHN * 64, NLAYER * CHN * CHN, NLAYER * CHN * CHN,
                     NLAYER * 3 * CHN * CHN, NLAYER * CHN * CHN,
                     NLAYER * 2 * CHN * CHN, NLAYER * 2 * CHN * CHN};
        int cum = 0;
        for (int i = 0; i < 8; ++i) {
            j.src[i] = srcs[i]; j.hi[i] = his[i]; j.lo[i] = los[i];
            cum += ns[i] / 256;
            j.blk_end[i] = cum;
        }
        k_split8<<<dim3(cum), dim3(256), 0, stream>>>(j);
    }

    k_bnprep<<<dim3((NLAYER * 3 * CHN + 255) / 256), dim3(256), 0, stream>>>(
        bn_g, bn_bb, bn_m, bn_v, bn_scale, bn_shift);

    k_zero_u32<<<dim3(NODES / 256), dim3(256), 0, stream>>>(counts, NODES);
    k_count<<<dim3(NEDGE / 256), dim3(256), 0, stream>>>(e_dst, counts);
    k_scan<<<dim3(1), dim3(256), 0, stream>>>(counts, offsets, cursor);
    k_fill<<<dim3(NEDGE / 256), dim3(256), 0, stream>>>(e_src, e_dst, edge_attr,
                                                        cursor, csr_sa);

    // node projection: h = x @ node_w^T + node_b
    k_gemm<<<dim3(NODES / 64, CHN / 32), dim3(256), 0, stream>>>(
        x_hi, x_lo, node_w_hi, node_w_lo, node_b, h_f32, h_hi, h_lo, 64, CHN);

    for (int l = 0; l < NLAYER; ++l) {
        size_t wo = (size_t)l * CHN * CHN;
        const float* sc0 = bn_scale + (l * 3 + 0) * CHN;
        const float* sh0 = bn_shift + (l * 3 + 0) * CHN;
        const float* sc1 = bn_scale + (l * 3 + 1) * CHN;
        const float* sh1 = bn_shift + (l * 3 + 1) * CHN;
        const float* sc2 = bn_scale + (l * 3 + 2) * CHN;
        const float* sh2 = bn_shift + (l * 3 + 2) * CHN;

        // agg (4096 blocks) ∥ qkv (3072 blocks)
        k_aggqkv<<<dim3(NODES / 4 + 3072), dim3(256), 0, stream>>>(
            h_hi, h_f32, offsets, csr_sa, edge_w, edge_b, zao_hi, zao_lo,
            h_lo, aiw_hi + wo * 3, aiw_lo + wo * 3, attn_in_b + l * 3 * CHN,
            q_hi, q_lo, kk_hi, kk_lo, vt_hi);
        // gine (256 blocks) ∥ attn (512 blocks)
        k_gineattn<<<dim3(NODES / 64 + 512), dim3(256), 0, stream>>>(
            zao_hi, zao_lo, gw1_hi + wo, gw1_lo + wo, gine_b1 + l * CHN,
            gw2_hi + wo, gw2_lo + wo, gine_b2 + l * CHN, h_f32, sc0, sh0, h1_f32,
            q_hi, q_lo, kk_hi, kk_lo, vt_hi, zao_hi, zao_lo);
        // out-proj + FFN
        k_outffn<<<dim3(NODES / 32), dim3(256), 0, stream>>>(
            zao_hi, zao_lo, aow_hi + wo, aow_lo + wo, attn_out_b + l * CHN,
            h_f32, sc1, sh1, h1_f32,
            mw1_hi + wo * 2, mw1_lo + wo * 2, mlp_b1 + l * 2 * CHN,
            mw2_hi + wo * 2, mw2_lo + wo * 2, mlp_b2 + l * CHN, sc2, sh2,
            h_f32, h_hi, h_lo);
    }

    k_zero_u32<<<dim3(NG * CHN / 256), dim3(256), 0, stream>>>((u32*)pool, NG * CHN);
    k_pool<<<dim3(NG, 8), dim3(128), 0, stream>>>(h_f32, pool);
    k_head<<<dim3(1), dim3(256), 0, stream>>>(pool, head_w1, head_b1, head_w2,
                                              head_b2, head_w3, head_b3,
                                              (float*)d_out);
}